// Round 14
// baseline (195.694 us; speedup 1.0000x reference)
//
#include <hip/hip_runtime.h>
#include <hip/hip_bf16.h>

// MHA fwd: B=2, S=2048, D=1024, H=16, HD=64. fp32 in/out, bf16 MFMA internals.
// R24 = R23 + ONE change: attn __launch_bounds__ (256,3) -> (256,4).
// The 3-bound was a fossil from R10's 49KB-LDS attn; since R16 LDS=32KB and
// VGPR=84, so 4 blocks/CU is feasible and grid(1024) = exactly 4/CU -> whole
// grid co-resident (+33% TLP in a latency-bound kernel, no 2nd dispatch wave).
// R23 lineage: prep merged (neutral, kept); qkv R8 128x64 @ (32,16,3);
// attn R17 32x32x16 in-register-P; out 64x64.

typedef __bf16 bf16x8 __attribute__((ext_vector_type(8)));
typedef __bf16 bf16x4 __attribute__((ext_vector_type(4)));
typedef __bf16 bf16x2 __attribute__((ext_vector_type(2)));
typedef float f32x4 __attribute__((ext_vector_type(4)));
typedef float f32x16 __attribute__((ext_vector_type(16)));
typedef unsigned int u32x4 __attribute__((ext_vector_type(4)));

#define S_LEN 2048
#define DMODEL 1024
#define NHEAD 16
#define HDIM 64
#define MROWS 4096  // B*S

#define AS1 __attribute__((address_space(1)))
#define AS3 __attribute__((address_space(3)))

#define QSCALE 0.18033688f  // 0.125 * log2e: scores come out in log2 units

// ---- prep: weight transpose+cast (z=0..3) and x cast (z=4), one dispatch ----
__global__ void prep_kernel(
    const float* __restrict__ X, __bf16* __restrict__ Xb,
    const float* __restrict__ W0, const float* __restrict__ W1,
    const float* __restrict__ W2, const float* __restrict__ W3,
    __bf16* __restrict__ T0, __bf16* __restrict__ T1,
    __bf16* __restrict__ T2, __bf16* __restrict__ T3) {
    __shared__ float tile[32][33];
    if (blockIdx.z == 4) {
        // cast: 1024 (x,y) blocks x 256 threads x 16 elems = 4.19M floats
        const int bid = blockIdx.y * 32 + blockIdx.x;
        const int tid = threadIdx.y * 32 + threadIdx.x;
        const int i = (bid * 256 + tid) * 16;
#pragma unroll
        for (int c = 0; c < 4; c++) {
            float4 f = *(const float4*)&X[i + c * 4];
            Xb[i + c * 4 + 0] = (__bf16)f.x;
            Xb[i + c * 4 + 1] = (__bf16)f.y;
            Xb[i + c * 4 + 2] = (__bf16)f.z;
            Xb[i + c * 4 + 3] = (__bf16)f.w;
        }
        return;
    }
    const float* W = (blockIdx.z == 0) ? W0 : (blockIdx.z == 1) ? W1 : (blockIdx.z == 2) ? W2 : W3;
    __bf16* WT = (blockIdx.z == 0) ? T0 : (blockIdx.z == 1) ? T1 : (blockIdx.z == 2) ? T2 : T3;
    int bx = blockIdx.x, by = blockIdx.y;
    int tx = threadIdx.x;
    for (int i = threadIdx.y; i < 32; i += 8)
        tile[i][tx] = W[(size_t)(by * 32 + i) * DMODEL + bx * 32 + tx];
    __syncthreads();
    for (int i = threadIdx.y; i < 32; i += 8)
        WT[(size_t)(bx * 32 + i) * DMODEL + by * 32 + tx] = (__bf16)tile[tx][i];
}

// ------------- GEMM QKV: 128x64 tile, BK=64, glds(16B) + XOR swizzle ---------
__global__ __launch_bounds__(256) void gemm_qkv_kernel(
    const __bf16* __restrict__ X,
    const __bf16* __restrict__ WqT, const __bf16* __restrict__ WkT, const __bf16* __restrict__ WvT,
    const float* __restrict__ bq, const float* __restrict__ bk, const float* __restrict__ bv,
    __bf16* __restrict__ Q, __bf16* __restrict__ K, __bf16* __restrict__ Vt) {
    const int which = blockIdx.z;
    const __bf16* Bt = (which == 0) ? WqT : (which == 1) ? WkT : WvT;
    const float* bias = (which == 0) ? bq : (which == 1) ? bk : bv;
    __bf16* Out = (which == 0) ? Q : (which == 1) ? K : Vt;

    __shared__ alignas(16) __bf16 As[128 * 64];
    __shared__ alignas(16) __bf16 Bs[64 * 64];

    const int tid = threadIdx.x;
    const int lane = tid & 63;
    const int wave = tid >> 6;
    const int wm = wave >> 1, wn = wave & 1;
    const int quad = lane >> 4;
    const int l16 = lane & 15;
    const int m0 = blockIdx.x * 128;   // m-tile on x (XCD locality)
    const int n0 = blockIdx.y * 64;
    const int r8 = lane >> 3;
    const int sc8 = ((lane & 7) ^ r8) * 8;
    const int gq0 = ((0 + quad) ^ (l16 & 7)) * 8;
    const int gq1 = ((4 + quad) ^ (l16 & 7)) * 8;

    f32x4 acc[4][2] = {};

    for (int k0 = 0; k0 < DMODEL; k0 += 64) {
        __syncthreads();
#pragma unroll
        for (int p = 0; p < 4; p++) {  // A: 128 rows
            const int row = wave * 32 + p * 8;
            __builtin_amdgcn_global_load_lds(
                (const AS1 void*)&X[(size_t)(m0 + row + r8) * DMODEL + k0 + sc8],
                (AS3 void*)&As[row * 64], 16, 0, 0);
        }
#pragma unroll
        for (int p = 0; p < 2; p++) {  // B: 64 rows
            const int row = wave * 16 + p * 8;
            __builtin_amdgcn_global_load_lds(
                (const AS1 void*)&Bt[(size_t)(n0 + row + r8) * DMODEL + k0 + sc8],
                (AS3 void*)&Bs[row * 64], 16, 0, 0);
        }
        __syncthreads();
#pragma unroll
        for (int ks = 0; ks < 2; ks++) {
            const int g = ks ? gq1 : gq0;
            bf16x8 af[4], bfr[2];
#pragma unroll
            for (int t = 0; t < 4; t++)
                af[t] = *(bf16x8*)&As[(wm * 64 + t * 16 + l16) * 64 + g];
#pragma unroll
            for (int t = 0; t < 2; t++)
                bfr[t] = *(bf16x8*)&Bs[(wn * 32 + t * 16 + l16) * 64 + g];
#pragma unroll
            for (int mt = 0; mt < 4; mt++)
#pragma unroll
                for (int nt = 0; nt < 2; nt++)
                    acc[mt][nt] = __builtin_amdgcn_mfma_f32_16x16x32_bf16(af[mt], bfr[nt], acc[mt][nt], 0, 0, 0);
        }
    }

    // C/D layout: col = lane&15, row = quad*4 + reg  [m89-verified]
#pragma unroll
    for (int mt = 0; mt < 4; mt++)
#pragma unroll
        for (int nt = 0; nt < 2; nt++) {
            const int n = n0 + wn * 32 + nt * 16 + l16;
            const float bn = bias[n];
            const int h = n >> 6, hd = n & 63;
            const int mbase = m0 + wm * 64 + mt * 16 + quad * 4;
            if (which == 2) {
                __bf16 pk[4];
#pragma unroll
                for (int r = 0; r < 4; r++) pk[r] = (__bf16)(acc[mt][nt][r] + bn);
                const int m = mbase;
                const int b = m >> 11, s = m & 2047;
                *(uint2*)&Out[(((size_t)(b * NHEAD + h) * HDIM + hd) * S_LEN) + s] = *(uint2*)pk;
            } else {
                const float sc = (which == 0) ? QSCALE : 1.0f;  // Q: fold 1/8 * log2e
#pragma unroll
                for (int r = 0; r < 4; r++) {
                    const int m = mbase + r;
                    const int b = m >> 11, s = m & 2047;
                    Out[(((size_t)(b * NHEAD + h) * S_LEN + s) * HDIM) + hd] =
                        (__bf16)((acc[mt][nt][r] + bn) * sc);
                }
            }
        }
}

// ------------- GEMM OUT: 64x64 tile, BK=64, grid (64,16): m-tile on x --------
__global__ __launch_bounds__(256) void gemm_out_kernel(
    const __bf16* __restrict__ A, const __bf16* __restrict__ Bt,
    const float* __restrict__ bias, float* __restrict__ Y) {
    __shared__ alignas(16) __bf16 As[64 * 64];
    __shared__ alignas(16) __bf16 Bs[64 * 64];

    const int tid = threadIdx.x;
    const int lane = tid & 63;
    const int wave = tid >> 6;
    const int wm = wave >> 1, wn = wave & 1;
    const int quad = lane >> 4;
    const int l16 = lane & 15;
    const int m0 = blockIdx.x * 64;    // m-tile on x (XCD locality)
    const int n0 = blockIdx.y * 64;
    const int r8 = lane >> 3;
    const int sc8 = ((lane & 7) ^ r8) * 8;
    const int gq0 = ((0 + quad) ^ (l16 & 7)) * 8;
    const int gq1 = ((4 + quad) ^ (l16 & 7)) * 8;

    f32x4 acc[2][2] = {};

    for (int k0 = 0; k0 < DMODEL; k0 += 64) {
        __syncthreads();
#pragma unroll
        for (int p = 0; p < 2; p++) {
            const int row = wave * 16 + p * 8;
            __builtin_amdgcn_global_load_lds(
                (const AS1 void*)&A[(size_t)(m0 + row + r8) * DMODEL + k0 + sc8],
                (AS3 void*)&As[row * 64], 16, 0, 0);
            __builtin_amdgcn_global_load_lds(
                (const AS1 void*)&Bt[(size_t)(n0 + row + r8) * DMODEL + k0 + sc8],
                (AS3 void*)&Bs[row * 64], 16, 0, 0);
        }
        __syncthreads();
#pragma unroll
        for (int ks = 0; ks < 2; ks++) {
            const int g = ks ? gq1 : gq0;
            bf16x8 af[2], bfr[2];
#pragma unroll
            for (int t = 0; t < 2; t++) {
                af[t]  = *(bf16x8*)&As[(wm * 32 + t * 16 + l16) * 64 + g];
                bfr[t] = *(bf16x8*)&Bs[(wn * 32 + t * 16 + l16) * 64 + g];
            }
#pragma unroll
            for (int mt = 0; mt < 2; mt++)
#pragma unroll
                for (int nt = 0; nt < 2; nt++)
                    acc[mt][nt] = __builtin_amdgcn_mfma_f32_16x16x32_bf16(af[mt], bfr[nt], acc[mt][nt], 0, 0, 0);
        }
    }

#pragma unroll
    for (int mt = 0; mt < 2; mt++)
#pragma unroll
        for (int nt = 0; nt < 2; nt++)
#pragma unroll
            for (int r = 0; r < 4; r++) {
                int m = m0 + wm * 32 + mt * 16 + quad * 4 + r;
                int n = n0 + wn * 32 + nt * 16 + l16;
                Y[(size_t)m * DMODEL + n] = acc[mt][nt][r] + bias[n];
            }
}

// -------- flash attention (R8/R17: 32x32x16 MFMA, in-register P) -------------
// Ks[128 k][64 hd] (chunk ^= row&7), Vs[64 hd][128 k] (chunk ^= hd&15).
// Wave (wq,wk): 32 q-rows x 64 k-cols. Swapped QK: sacc = mfma(K,Q) = S^T,
// lane = q-col (lane&31), 16 k-rows via (r&3)+8*(r>>2)+4*(lane>>5).
// PA frags assembled via bf16-pack + shfl_xor(32). O += mfma(PA, V);
// l += mfma(PA, ones). V chunks offset by k-half (kl0>>3).
// Epilogue: k-half partials reduced via LDS scratch (stride 49 f32).

static __device__ __forceinline__ unsigned pkbf2(float a, float b) {
    bf16x2 t;
    t[0] = (__bf16)a;
    t[1] = (__bf16)b;
    return __builtin_bit_cast(unsigned, t);
}

template <bool MASK>
__device__ __forceinline__ void attn_tile32(
    const __bf16* Ks, const __bf16* Vs,
    const bf16x8 (&qf)[4], const bf16x8& onesf,
    f32x16 (&oacc)[2], f32x16& lacc,
    int q_lane, int kl0, int kabs0, int lane) {
    const int l32 = lane & 31, hi = lane >> 5, l7 = lane & 7, l15 = lane & 15;
    const int cbase = kl0 >> 3;   // wave's V chunk base (0 or 8)
    bf16x8 pa[4];
#pragma unroll
    for (int sub = 0; sub < 2; sub++) {
        f32x16 s = {};
        const int row = kl0 + sub * 32 + l32;
#pragma unroll
        for (int j = 0; j < 4; j++) {
            const int ch = ((2 * j + hi) ^ l7) * 8;
            bf16x8 kf = *(const bf16x8*)&Ks[row * 64 + ch];
            s = __builtin_amdgcn_mfma_f32_32x32x16_bf16(kf, qf[j], s, 0, 0, 0);
        }
        float p[16];
#pragma unroll
        for (int r = 0; r < 16; r++) {
            const float e = __builtin_amdgcn_exp2f(s[r]);
            if (MASK) {
                const int kabs = kabs0 + sub * 32 + (r & 3) + 8 * (r >> 2) + 4 * hi;
                p[r] = (kabs > q_lane) ? 0.0f : e;
            } else {
                p[r] = e;
            }
        }
        const unsigned c0 = pkbf2(p[0], p[1]),   c1 = pkbf2(p[2], p[3]);
        const unsigned c2 = pkbf2(p[4], p[5]),   c3 = pkbf2(p[6], p[7]);
        const unsigned c4 = pkbf2(p[8], p[9]),   c5 = pkbf2(p[10], p[11]);
        const unsigned c6 = pkbf2(p[12], p[13]), c7 = pkbf2(p[14], p[15]);
        const unsigned sA0 = hi ? c0 : c2, sA1 = hi ? c1 : c3;
        const unsigned rA0 = __shfl_xor(sA0, 32, 64), rA1 = __shfl_xor(sA1, 32, 64);
        const unsigned sB0 = hi ? c4 : c6, sB1 = hi ? c5 : c7;
        const unsigned rB0 = __shfl_xor(sB0, 32, 64), rB1 = __shfl_xor(sB1, 32, 64);
        u32x4 wA, wB;
        if (hi) {
            wA[0] = rA0; wA[1] = rA1; wA[2] = c2; wA[3] = c3;
            wB[0] = rB0; wB[1] = rB1; wB[2] = c6; wB[3] = c7;
        } else {
            wA[0] = c0; wA[1] = c1; wA[2] = rA0; wA[3] = rA1;
            wB[0] = c4; wB[1] = c5; wB[2] = rB0; wB[3] = rB1;
        }
        pa[sub * 2]     = __builtin_bit_cast(bf16x8, wA);
        pa[sub * 2 + 1] = __builtin_bit_cast(bf16x8, wB);
    }
#pragma unroll
    for (int kblk = 0; kblk < 4; kblk++) {
#pragma unroll
        for (int dsub = 0; dsub < 2; dsub++) {
            const int hd = dsub * 32 + l32;
            const int ch = ((cbase + kblk * 2 + hi) ^ l15) * 8;
            bf16x8 vf = *(const bf16x8*)&Vs[hd * 128 + ch];
            oacc[dsub] = __builtin_amdgcn_mfma_f32_32x32x16_bf16(pa[kblk], vf, oacc[dsub], 0, 0, 0);
        }
        lacc = __builtin_amdgcn_mfma_f32_32x32x16_bf16(pa[kblk], onesf, lacc, 0, 0, 0);
    }
}

__global__ __launch_bounds__(256, 4) void attn_kernel(
    const __bf16* __restrict__ Q, const __bf16* __restrict__ K, const __bf16* __restrict__ Vt,
    __bf16* __restrict__ Aout) {
    const int id = blockIdx.x;
    const int bh = id & 31;                 // XCD-pinned: id%8 == bh%8
    const int qt = 31 - (id >> 5);          // big tiles first
    const int b = bh >> 4, h = bh & 15;
    const int tid = threadIdx.x, lane = tid & 63, wave = tid >> 6;
    const int wq = wave >> 1, wk = wave & 1;
    const int l32 = lane & 31, hi = lane >> 5;

    __shared__ alignas(16) __bf16 SMEM[128 * 64 + 64 * 128];  // Ks | Vs (32 KB)
    __bf16* Ks = SMEM;
    __bf16* Vs = SMEM + 128 * 64;

    const size_t base = (size_t)bh * S_LEN * HDIM;   // same for Q, K, Vt
    const int q0 = qt * 64;
    const int q_lane = q0 + wq * 32 + l32;

    bf16x8 qf[4];
#pragma unroll
    for (int j = 0; j < 4; j++)
        qf[j] = *(const bf16x8*)&Q[base + (size_t)q_lane * HDIM + j * 16 + hi * 8];

    bf16x8 onesf;
#pragma unroll
    for (int jj = 0; jj < 8; jj++) onesf[jj] = (__bf16)1.0f;

    f32x16 oacc[2] = {};
    f32x16 lacc = {};

    // staging lane roles
    const int r8k = lane >> 3;
    const int sck = ((lane & 7) ^ r8k) * 8;   // K source chunk (elems)
    const int r4v = lane >> 4;                // V: 4 rows per glds

    const int kb_all = (qt >> 1) + 1;
    const int kl0 = wk * 64;                  // this wave's local k base

    for (int kb = 0; kb < kb_all; kb++) {
        const int k0 = kb * 128;
        __syncthreads();
#pragma unroll
        for (int p = 0; p < 4; p++) {  // K: 128 rows, 8 rows/glds
            const int row = wave * 32 + p * 8;
            __builtin_amdgcn_global_load_lds(
                (const AS1 void*)&K[base + (size_t)(k0 + row + r8k) * HDIM + sck],
                (AS3 void*)&Ks[row * 64], 16, 0, 0);
        }
#pragma unroll
        for (int p = 0; p < 4; p++) {  // V^T: 64 rows x 128 cols, 4 rows/glds
            const int row = wave * 16 + p * 4;
            const int lc = ((lane & 15) ^ ((p * 4 + r4v) & 15)) * 8;
            __builtin_amdgcn_global_load_lds(
                (const AS1 void*)&Vt[base + (size_t)(row + r4v) * S_LEN + k0 + lc],
                (AS3 void*)&Vs[row * 128], 16, 0, 0);
        }
        __syncthreads();

        if (kb == kb_all - 1)
            attn_tile32<true>(Ks, Vs, qf, onesf, oacc, lacc, q_lane, kl0, k0 + kl0, lane);
        else
            attn_tile32<false>(Ks, Vs, qf, onesf, oacc, lacc, q_lane, kl0, k0 + kl0, lane);
    }

    // ---- k-half reduction via LDS scratch (stride 49 f32: conflict-free) ----
    __syncthreads();
    float* scr = (float*)SMEM;
    const int slot = (wq * 64 + lane) * 49;
    if (wk) {
#pragma unroll
        for (int ss = 0; ss < 2; ss++)
#pragma unroll
            for (int r = 0; r < 16; r++) scr[slot + ss * 16 + r] = oacc[ss][r];
#pragma unroll
        for (int r = 0; r < 16; r++) scr[slot + 32 + r] = lacc[r];
    }
    __syncthreads();
    if (!wk) {
#pragma unroll
        for (int ss = 0; ss < 2; ss++)
#pragma unroll
            for (int r = 0; r < 16; r++) oacc[ss][r] += scr[slot + ss * 16 + r];
#pragma unroll
        for (int r = 0; r < 16; r++) lacc[r] += scr[slot + 32 + r];
        float rl[16];
#pragma unroll
        for (int r = 0; r < 16; r++) rl[r] = 1.0f / lacc[r];
#pragma unroll
        for (int ss = 0; ss < 2; ss++)
#pragma unroll
            for (int r = 0; r < 16; r++) {
                const int q = q0 + wq * 32 + (r & 3) + 8 * (r >> 2) + 4 * hi;
                Aout[(size_t)(b * S_LEN + q) * DMODEL + h * 64 + ss * 32 + l32] =
                    (__bf16)(oacc[ss][r] * rl[r]);
            }
    }
}

extern "C" void kernel_launch(void* const* d_in, const int* in_sizes, int n_in,
                              void* d_out, int out_size, void* d_ws, size_t ws_size,
                              hipStream_t stream) {
    const float* x  = (const float*)d_in[0];
    // d_in[1] = mask: causal triu, reproduced analytically
    const float* wq = (const float*)d_in[2];
    const float* bq = (const float*)d_in[3];
    const float* wk = (const float*)d_in[4];
    const float* bk = (const float*)d_in[5];
    const float* wv = (const float*)d_in[6];
    const float* bv = (const float*)d_in[7];
    const float* wo = (const float*)d_in[8];
    const float* bo = (const float*)d_in[9];
    float* out = (float*)d_out;

    char* ws = (char*)d_ws;
    __bf16* xb  = (__bf16*)(ws);                          // 8 MiB
    __bf16* wqT = (__bf16*)(ws + ((size_t)8  << 20));     // 2 MiB each
    __bf16* wkT = (__bf16*)(ws + ((size_t)10 << 20));
    __bf16* wvT = (__bf16*)(ws + ((size_t)12 << 20));
    __bf16* woT = (__bf16*)(ws + ((size_t)14 << 20));
    __bf16* Qb  = (__bf16*)(ws + ((size_t)16 << 20));     // 8 MiB each
    __bf16* Kb  = (__bf16*)(ws + ((size_t)24 << 20));
    __bf16* Vtb = (__bf16*)(ws + ((size_t)32 << 20));     // V^T [B,H,HD,S]
    __bf16* Ab  = (__bf16*)(ws + ((size_t)40 << 20));     // 8 MiB

    prep_kernel<<<dim3(32, 32, 5), dim3(32, 8), 0, stream>>>(
        x, xb, wq, wk, wv, wo, wqT, wkT, wvT, woT);
    gemm_qkv_kernel<<<dim3(32, 16, 3), 256, 0, stream>>>(xb, wqT, wkT, wvT, bq, bk, bv, Qb, Kb, Vtb);
    attn_kernel<<<1024, 256, 0, stream>>>(Qb, Kb, Vtb, Ab);
    gemm_out_kernel<<<dim3(64, 16), 256, 0, stream>>>(Ab, woT, bo, out);
}

// Round 15
// 186.007 us; speedup vs baseline: 1.0521x; 1.0521x over previous
//
#include <hip/hip_runtime.h>
#include <hip/hip_bf16.h>

// MHA fwd: B=2, S=2048, D=1024, H=16, HD=64. fp32 in/out, bf16 MFMA internals.
// R25 = R23 exact revert (best verified: 183.6us, stable across R8/R13/R23).
// R24's (256,4) bound REVERTED: it squeezed VGPR 84->64 -> ~58MB/dispatch of
// scratch spill traffic (FETCH 12->32MB, WRITE 8->45MB), attn 38->49.5us.
// Session falsification map (all mechanism-identified):
//   qkv: density up (R12) / dbuf drain-0 (R19) / reg-stage+cast-fuse (R20) /
//        QKV-fusion (R22, X re-reads were L2 hits) — all regress; 128x64 @
//        (32,16,3) 2-barrier glds is the local optimum (~40.8us).
//   attn: reg-stage T14 (R13, bank conflicts) / dbuf (R15) / V-direct (R21,
//        hd-strided gather) / setprio (R20) / occ-bound (R24, spills) —
//        regress; 32x32x16 swapped-QK in-register-P @ (256,3) is optimum.
//   prep-merge (R23): neutral, kept. Untested-and-out-of-budget: counted
//   vmcnt(N) inline-asm schedule (T4) on attn.

typedef __bf16 bf16x8 __attribute__((ext_vector_type(8)));
typedef __bf16 bf16x4 __attribute__((ext_vector_type(4)));
typedef __bf16 bf16x2 __attribute__((ext_vector_type(2)));
typedef float f32x4 __attribute__((ext_vector_type(4)));
typedef float f32x16 __attribute__((ext_vector_type(16)));
typedef unsigned int u32x4 __attribute__((ext_vector_type(4)));

#define S_LEN 2048
#define DMODEL 1024
#define NHEAD 16
#define HDIM 64
#define MROWS 4096  // B*S

#define AS1 __attribute__((address_space(1)))
#define AS3 __attribute__((address_space(3)))

#define QSCALE 0.18033688f  // 0.125 * log2e: scores come out in log2 units

// ---- prep: weight transpose+cast (z=0..3) and x cast (z=4), one dispatch ----
__global__ void prep_kernel(
    const float* __restrict__ X, __bf16* __restrict__ Xb,
    const float* __restrict__ W0, const float* __restrict__ W1,
    const float* __restrict__ W2, const float* __restrict__ W3,
    __bf16* __restrict__ T0, __bf16* __restrict__ T1,
    __bf16* __restrict__ T2, __bf16* __restrict__ T3) {
    __shared__ float tile[32][33];
    if (blockIdx.z == 4) {
        // cast: 1024 (x,y) blocks x 256 threads x 16 elems = 4.19M floats
        const int bid = blockIdx.y * 32 + blockIdx.x;
        const int tid = threadIdx.y * 32 + threadIdx.x;
        const int i = (bid * 256 + tid) * 16;
#pragma unroll
        for (int c = 0; c < 4; c++) {
            float4 f = *(const float4*)&X[i + c * 4];
            Xb[i + c * 4 + 0] = (__bf16)f.x;
            Xb[i + c * 4 + 1] = (__bf16)f.y;
            Xb[i + c * 4 + 2] = (__bf16)f.z;
            Xb[i + c * 4 + 3] = (__bf16)f.w;
        }
        return;
    }
    const float* W = (blockIdx.z == 0) ? W0 : (blockIdx.z == 1) ? W1 : (blockIdx.z == 2) ? W2 : W3;
    __bf16* WT = (blockIdx.z == 0) ? T0 : (blockIdx.z == 1) ? T1 : (blockIdx.z == 2) ? T2 : T3;
    int bx = blockIdx.x, by = blockIdx.y;
    int tx = threadIdx.x;
    for (int i = threadIdx.y; i < 32; i += 8)
        tile[i][tx] = W[(size_t)(by * 32 + i) * DMODEL + bx * 32 + tx];
    __syncthreads();
    for (int i = threadIdx.y; i < 32; i += 8)
        WT[(size_t)(bx * 32 + i) * DMODEL + by * 32 + tx] = (__bf16)tile[tx][i];
}

// ------------- GEMM QKV: 128x64 tile, BK=64, glds(16B) + XOR swizzle ---------
__global__ __launch_bounds__(256) void gemm_qkv_kernel(
    const __bf16* __restrict__ X,
    const __bf16* __restrict__ WqT, const __bf16* __restrict__ WkT, const __bf16* __restrict__ WvT,
    const float* __restrict__ bq, const float* __restrict__ bk, const float* __restrict__ bv,
    __bf16* __restrict__ Q, __bf16* __restrict__ K, __bf16* __restrict__ Vt) {
    const int which = blockIdx.z;
    const __bf16* Bt = (which == 0) ? WqT : (which == 1) ? WkT : WvT;
    const float* bias = (which == 0) ? bq : (which == 1) ? bk : bv;
    __bf16* Out = (which == 0) ? Q : (which == 1) ? K : Vt;

    __shared__ alignas(16) __bf16 As[128 * 64];
    __shared__ alignas(16) __bf16 Bs[64 * 64];

    const int tid = threadIdx.x;
    const int lane = tid & 63;
    const int wave = tid >> 6;
    const int wm = wave >> 1, wn = wave & 1;
    const int quad = lane >> 4;
    const int l16 = lane & 15;
    const int m0 = blockIdx.x * 128;   // m-tile on x (XCD locality)
    const int n0 = blockIdx.y * 64;
    const int r8 = lane >> 3;
    const int sc8 = ((lane & 7) ^ r8) * 8;
    const int gq0 = ((0 + quad) ^ (l16 & 7)) * 8;
    const int gq1 = ((4 + quad) ^ (l16 & 7)) * 8;

    f32x4 acc[4][2] = {};

    for (int k0 = 0; k0 < DMODEL; k0 += 64) {
        __syncthreads();
#pragma unroll
        for (int p = 0; p < 4; p++) {  // A: 128 rows
            const int row = wave * 32 + p * 8;
            __builtin_amdgcn_global_load_lds(
                (const AS1 void*)&X[(size_t)(m0 + row + r8) * DMODEL + k0 + sc8],
                (AS3 void*)&As[row * 64], 16, 0, 0);
        }
#pragma unroll
        for (int p = 0; p < 2; p++) {  // B: 64 rows
            const int row = wave * 16 + p * 8;
            __builtin_amdgcn_global_load_lds(
                (const AS1 void*)&Bt[(size_t)(n0 + row + r8) * DMODEL + k0 + sc8],
                (AS3 void*)&Bs[row * 64], 16, 0, 0);
        }
        __syncthreads();
#pragma unroll
        for (int ks = 0; ks < 2; ks++) {
            const int g = ks ? gq1 : gq0;
            bf16x8 af[4], bfr[2];
#pragma unroll
            for (int t = 0; t < 4; t++)
                af[t] = *(bf16x8*)&As[(wm * 64 + t * 16 + l16) * 64 + g];
#pragma unroll
            for (int t = 0; t < 2; t++)
                bfr[t] = *(bf16x8*)&Bs[(wn * 32 + t * 16 + l16) * 64 + g];
#pragma unroll
            for (int mt = 0; mt < 4; mt++)
#pragma unroll
                for (int nt = 0; nt < 2; nt++)
                    acc[mt][nt] = __builtin_amdgcn_mfma_f32_16x16x32_bf16(af[mt], bfr[nt], acc[mt][nt], 0, 0, 0);
        }
    }

    // C/D layout: col = lane&15, row = quad*4 + reg  [m89-verified]
#pragma unroll
    for (int mt = 0; mt < 4; mt++)
#pragma unroll
        for (int nt = 0; nt < 2; nt++) {
            const int n = n0 + wn * 32 + nt * 16 + l16;
            const float bn = bias[n];
            const int h = n >> 6, hd = n & 63;
            const int mbase = m0 + wm * 64 + mt * 16 + quad * 4;
            if (which == 2) {
                __bf16 pk[4];
#pragma unroll
                for (int r = 0; r < 4; r++) pk[r] = (__bf16)(acc[mt][nt][r] + bn);
                const int m = mbase;
                const int b = m >> 11, s = m & 2047;
                *(uint2*)&Out[(((size_t)(b * NHEAD + h) * HDIM + hd) * S_LEN) + s] = *(uint2*)pk;
            } else {
                const float sc = (which == 0) ? QSCALE : 1.0f;  // Q: fold 1/8 * log2e
#pragma unroll
                for (int r = 0; r < 4; r++) {
                    const int m = mbase + r;
                    const int b = m >> 11, s = m & 2047;
                    Out[(((size_t)(b * NHEAD + h) * S_LEN + s) * HDIM) + hd] =
                        (__bf16)((acc[mt][nt][r] + bn) * sc);
                }
            }
        }
}

// ------------- GEMM OUT: 64x64 tile, BK=64, grid (64,16): m-tile on x --------
__global__ __launch_bounds__(256) void gemm_out_kernel(
    const __bf16* __restrict__ A, const __bf16* __restrict__ Bt,
    const float* __restrict__ bias, float* __restrict__ Y) {
    __shared__ alignas(16) __bf16 As[64 * 64];
    __shared__ alignas(16) __bf16 Bs[64 * 64];

    const int tid = threadIdx.x;
    const int lane = tid & 63;
    const int wave = tid >> 6;
    const int wm = wave >> 1, wn = wave & 1;
    const int quad = lane >> 4;
    const int l16 = lane & 15;
    const int m0 = blockIdx.x * 64;    // m-tile on x (XCD locality)
    const int n0 = blockIdx.y * 64;
    const int r8 = lane >> 3;
    const int sc8 = ((lane & 7) ^ r8) * 8;
    const int gq0 = ((0 + quad) ^ (l16 & 7)) * 8;
    const int gq1 = ((4 + quad) ^ (l16 & 7)) * 8;

    f32x4 acc[2][2] = {};

    for (int k0 = 0; k0 < DMODEL; k0 += 64) {
        __syncthreads();
#pragma unroll
        for (int p = 0; p < 2; p++) {
            const int row = wave * 16 + p * 8;
            __builtin_amdgcn_global_load_lds(
                (const AS1 void*)&A[(size_t)(m0 + row + r8) * DMODEL + k0 + sc8],
                (AS3 void*)&As[row * 64], 16, 0, 0);
            __builtin_amdgcn_global_load_lds(
                (const AS1 void*)&Bt[(size_t)(n0 + row + r8) * DMODEL + k0 + sc8],
                (AS3 void*)&Bs[row * 64], 16, 0, 0);
        }
        __syncthreads();
#pragma unroll
        for (int ks = 0; ks < 2; ks++) {
            const int g = ks ? gq1 : gq0;
            bf16x8 af[2], bfr[2];
#pragma unroll
            for (int t = 0; t < 2; t++) {
                af[t]  = *(bf16x8*)&As[(wm * 32 + t * 16 + l16) * 64 + g];
                bfr[t] = *(bf16x8*)&Bs[(wn * 32 + t * 16 + l16) * 64 + g];
            }
#pragma unroll
            for (int mt = 0; mt < 2; mt++)
#pragma unroll
                for (int nt = 0; nt < 2; nt++)
                    acc[mt][nt] = __builtin_amdgcn_mfma_f32_16x16x32_bf16(af[mt], bfr[nt], acc[mt][nt], 0, 0, 0);
        }
    }

#pragma unroll
    for (int mt = 0; mt < 2; mt++)
#pragma unroll
        for (int nt = 0; nt < 2; nt++)
#pragma unroll
            for (int r = 0; r < 4; r++) {
                int m = m0 + wm * 32 + mt * 16 + quad * 4 + r;
                int n = n0 + wn * 32 + nt * 16 + l16;
                Y[(size_t)m * DMODEL + n] = acc[mt][nt][r] + bias[n];
            }
}

// -------- flash attention (R8/R17: 32x32x16 MFMA, in-register P) -------------
// Ks[128 k][64 hd] (chunk ^= row&7), Vs[64 hd][128 k] (chunk ^= hd&15).
// Wave (wq,wk): 32 q-rows x 64 k-cols. Swapped QK: sacc = mfma(K,Q) = S^T,
// lane = q-col (lane&31), 16 k-rows via (r&3)+8*(r>>2)+4*(lane>>5).
// PA frags assembled via bf16-pack + shfl_xor(32). O += mfma(PA, V);
// l += mfma(PA, ones). V chunks offset by k-half (kl0>>3).
// Epilogue: k-half partials reduced via LDS scratch (stride 49 f32).

static __device__ __forceinline__ unsigned pkbf2(float a, float b) {
    bf16x2 t;
    t[0] = (__bf16)a;
    t[1] = (__bf16)b;
    return __builtin_bit_cast(unsigned, t);
}

template <bool MASK>
__device__ __forceinline__ void attn_tile32(
    const __bf16* Ks, const __bf16* Vs,
    const bf16x8 (&qf)[4], const bf16x8& onesf,
    f32x16 (&oacc)[2], f32x16& lacc,
    int q_lane, int kl0, int kabs0, int lane) {
    const int l32 = lane & 31, hi = lane >> 5, l7 = lane & 7, l15 = lane & 15;
    const int cbase = kl0 >> 3;   // wave's V chunk base (0 or 8)
    bf16x8 pa[4];
#pragma unroll
    for (int sub = 0; sub < 2; sub++) {
        f32x16 s = {};
        const int row = kl0 + sub * 32 + l32;
#pragma unroll
        for (int j = 0; j < 4; j++) {
            const int ch = ((2 * j + hi) ^ l7) * 8;
            bf16x8 kf = *(const bf16x8*)&Ks[row * 64 + ch];
            s = __builtin_amdgcn_mfma_f32_32x32x16_bf16(kf, qf[j], s, 0, 0, 0);
        }
        float p[16];
#pragma unroll
        for (int r = 0; r < 16; r++) {
            const float e = __builtin_amdgcn_exp2f(s[r]);
            if (MASK) {
                const int kabs = kabs0 + sub * 32 + (r & 3) + 8 * (r >> 2) + 4 * hi;
                p[r] = (kabs > q_lane) ? 0.0f : e;
            } else {
                p[r] = e;
            }
        }
        const unsigned c0 = pkbf2(p[0], p[1]),   c1 = pkbf2(p[2], p[3]);
        const unsigned c2 = pkbf2(p[4], p[5]),   c3 = pkbf2(p[6], p[7]);
        const unsigned c4 = pkbf2(p[8], p[9]),   c5 = pkbf2(p[10], p[11]);
        const unsigned c6 = pkbf2(p[12], p[13]), c7 = pkbf2(p[14], p[15]);
        const unsigned sA0 = hi ? c0 : c2, sA1 = hi ? c1 : c3;
        const unsigned rA0 = __shfl_xor(sA0, 32, 64), rA1 = __shfl_xor(sA1, 32, 64);
        const unsigned sB0 = hi ? c4 : c6, sB1 = hi ? c5 : c7;
        const unsigned rB0 = __shfl_xor(sB0, 32, 64), rB1 = __shfl_xor(sB1, 32, 64);
        u32x4 wA, wB;
        if (hi) {
            wA[0] = rA0; wA[1] = rA1; wA[2] = c2; wA[3] = c3;
            wB[0] = rB0; wB[1] = rB1; wB[2] = c6; wB[3] = c7;
        } else {
            wA[0] = c0; wA[1] = c1; wA[2] = rA0; wA[3] = rA1;
            wB[0] = c4; wB[1] = c5; wB[2] = rB0; wB[3] = rB1;
        }
        pa[sub * 2]     = __builtin_bit_cast(bf16x8, wA);
        pa[sub * 2 + 1] = __builtin_bit_cast(bf16x8, wB);
    }
#pragma unroll
    for (int kblk = 0; kblk < 4; kblk++) {
#pragma unroll
        for (int dsub = 0; dsub < 2; dsub++) {
            const int hd = dsub * 32 + l32;
            const int ch = ((cbase + kblk * 2 + hi) ^ l15) * 8;
            bf16x8 vf = *(const bf16x8*)&Vs[hd * 128 + ch];
            oacc[dsub] = __builtin_amdgcn_mfma_f32_32x32x16_bf16(pa[kblk], vf, oacc[dsub], 0, 0, 0);
        }
        lacc = __builtin_amdgcn_mfma_f32_32x32x16_bf16(pa[kblk], onesf, lacc, 0, 0, 0);
    }
}

__global__ __launch_bounds__(256, 3) void attn_kernel(
    const __bf16* __restrict__ Q, const __bf16* __restrict__ K, const __bf16* __restrict__ Vt,
    __bf16* __restrict__ Aout) {
    const int id = blockIdx.x;
    const int bh = id & 31;                 // XCD-pinned: id%8 == bh%8
    const int qt = 31 - (id >> 5);          // big tiles first
    const int b = bh >> 4, h = bh & 15;
    const int tid = threadIdx.x, lane = tid & 63, wave = tid >> 6;
    const int wq = wave >> 1, wk = wave & 1;
    const int l32 = lane & 31, hi = lane >> 5;

    __shared__ alignas(16) __bf16 SMEM[128 * 64 + 64 * 128];  // Ks | Vs (32 KB)
    __bf16* Ks = SMEM;
    __bf16* Vs = SMEM + 128 * 64;

    const size_t base = (size_t)bh * S_LEN * HDIM;   // same for Q, K, Vt
    const int q0 = qt * 64;
    const int q_lane = q0 + wq * 32 + l32;

    bf16x8 qf[4];
#pragma unroll
    for (int j = 0; j < 4; j++)
        qf[j] = *(const bf16x8*)&Q[base + (size_t)q_lane * HDIM + j * 16 + hi * 8];

    bf16x8 onesf;
#pragma unroll
    for (int jj = 0; jj < 8; jj++) onesf[jj] = (__bf16)1.0f;

    f32x16 oacc[2] = {};
    f32x16 lacc = {};

    // staging lane roles
    const int r8k = lane >> 3;
    const int sck = ((lane & 7) ^ r8k) * 8;   // K source chunk (elems)
    const int r4v = lane >> 4;                // V: 4 rows per glds

    const int kb_all = (qt >> 1) + 1;
    const int kl0 = wk * 64;                  // this wave's local k base

    for (int kb = 0; kb < kb_all; kb++) {
        const int k0 = kb * 128;
        __syncthreads();
#pragma unroll
        for (int p = 0; p < 4; p++) {  // K: 128 rows, 8 rows/glds
            const int row = wave * 32 + p * 8;
            __builtin_amdgcn_global_load_lds(
                (const AS1 void*)&K[base + (size_t)(k0 + row + r8k) * HDIM + sck],
                (AS3 void*)&Ks[row * 64], 16, 0, 0);
        }
#pragma unroll
        for (int p = 0; p < 4; p++) {  // V^T: 64 rows x 128 cols, 4 rows/glds
            const int row = wave * 16 + p * 4;
            const int lc = ((lane & 15) ^ ((p * 4 + r4v) & 15)) * 8;
            __builtin_amdgcn_global_load_lds(
                (const AS1 void*)&Vt[base + (size_t)(row + r4v) * S_LEN + k0 + lc],
                (AS3 void*)&Vs[row * 128], 16, 0, 0);
        }
        __syncthreads();

        if (kb == kb_all - 1)
            attn_tile32<true>(Ks, Vs, qf, onesf, oacc, lacc, q_lane, kl0, k0 + kl0, lane);
        else
            attn_tile32<false>(Ks, Vs, qf, onesf, oacc, lacc, q_lane, kl0, k0 + kl0, lane);
    }

    // ---- k-half reduction via LDS scratch (stride 49 f32: conflict-free) ----
    __syncthreads();
    float* scr = (float*)SMEM;
    const int slot = (wq * 64 + lane) * 49;
    if (wk) {
#pragma unroll
        for (int ss = 0; ss < 2; ss++)
#pragma unroll
            for (int r = 0; r < 16; r++) scr[slot + ss * 16 + r] = oacc[ss][r];
#pragma unroll
        for (int r = 0; r < 16; r++) scr[slot + 32 + r] = lacc[r];
    }
    __syncthreads();
    if (!wk) {
#pragma unroll
        for (int ss = 0; ss < 2; ss++)
#pragma unroll
            for (int r = 0; r < 16; r++) oacc[ss][r] += scr[slot + ss * 16 + r];
#pragma unroll
        for (int r = 0; r < 16; r++) lacc[r] += scr[slot + 32 + r];
        float rl[16];
#pragma unroll
        for (int r = 0; r < 16; r++) rl[r] = 1.0f / lacc[r];
#pragma unroll
        for (int ss = 0; ss < 2; ss++)
#pragma unroll
            for (int r = 0; r < 16; r++) {
                const int q = q0 + wq * 32 + (r & 3) + 8 * (r >> 2) + 4 * hi;
                Aout[(size_t)(b * S_LEN + q) * DMODEL + h * 64 + ss * 32 + l32] =
                    (__bf16)(oacc[ss][r] * rl[r]);
            }
    }
}

extern "C" void kernel_launch(void* const* d_in, const int* in_sizes, int n_in,
                              void* d_out, int out_size, void* d_ws, size_t ws_size,
                              hipStream_t stream) {
    const float* x  = (const float*)d_in[0];
    // d_in[1] = mask: causal triu, reproduced analytically
    const float* wq = (const float*)d_in[2];
    const float* bq = (const float*)d_in[3];
    const float* wk = (const float*)d_in[4];
    const float* bk = (const float*)d_in[5];
    const float* wv = (const float*)d_in[6];
    const float* bv = (const float*)d_in[7];
    const float* wo = (const float*)d_in[8];
    const float* bo = (const float*)d_in[9];
    float* out = (float*)d_out;

    char* ws = (char*)d_ws;
    __bf16* xb  = (__bf16*)(ws);                          // 8 MiB
    __bf16* wqT = (__bf16*)(ws + ((size_t)8  << 20));     // 2 MiB each
    __bf16* wkT = (__bf16*)(ws + ((size_t)10 << 20));
    __bf16* wvT = (__bf16*)(ws + ((size_t)12 << 20));
    __bf16* woT = (__bf16*)(ws + ((size_t)14 << 20));
    __bf16* Qb  = (__bf16*)(ws + ((size_t)16 << 20));     // 8 MiB each
    __bf16* Kb  = (__bf16*)(ws + ((size_t)24 << 20));
    __bf16* Vtb = (__bf16*)(ws + ((size_t)32 << 20));     // V^T [B,H,HD,S]
    __bf16* Ab  = (__bf16*)(ws + ((size_t)40 << 20));     // 8 MiB

    prep_kernel<<<dim3(32, 32, 5), dim3(32, 8), 0, stream>>>(
        x, xb, wq, wk, wv, wo, wqT, wkT, wvT, woT);
    gemm_qkv_kernel<<<dim3(32, 16, 3), 256, 0, stream>>>(xb, wqT, wkT, wvT, bq, bk, bv, Qb, Kb, Vtb);
    attn_kernel<<<1024, 256, 0, stream>>>(Qb, Kb, Vtb, Ab);
    gemm_out_kernel<<<dim3(64, 16), 256, 0, stream>>>(Ab, woT, bo, out);
}